// Round 8
// baseline (441.141 us; speedup 1.0000x reference)
//
#include <hip/hip_runtime.h>
#include <cstdint>
#include <cstddef>

// ---------- types ----------
typedef __attribute__((ext_vector_type(8))) short short8;     // 8 x bf16
typedef __attribute__((ext_vector_type(4))) float f32x4;
typedef __attribute__((ext_vector_type(4))) unsigned short ushort4v;
typedef __attribute__((ext_vector_type(2))) unsigned uint2v;

#define DEVI __device__ __forceinline__

DEVI unsigned short f2bf(float f) {  // RNE f32 -> bf16 bits
  union { float f; unsigned u; } x; x.f = f;
  unsigned r = x.u + 0x7fffu + ((x.u >> 16) & 1u);
  return (unsigned short)(r >> 16);
}

#define MFMA16(a, b, c) __builtin_amdgcn_mfma_f32_16x16x32_bf16(a, b, c, 0, 0, 0)
#define FENCE asm volatile("" ::: "memory")
#define WAITVM(n) asm volatile("s_waitcnt vmcnt(" #n ")" ::: "memory")
#define WAITLGKM0 asm volatile("s_waitcnt lgkmcnt(0)" ::: "memory")
#define BARRIER do { FENCE; __builtin_amdgcn_s_barrier(); FENCE; } while (0)

typedef __attribute__((address_space(1))) const void g_void;
typedef __attribute__((address_space(3))) void lds_void;
DEVI void gload_lds16(const void* g, void* l) {
  __builtin_amdgcn_global_load_lds((g_void*)g, (lds_void*)l, 16, 0, 0);
}

// ---------- constants ----------
static constexpr int DM = 1024;   // d_model
static constexpr int NH = 16;     // heads
static constexpr int DK = 64;     // head dim
static constexpr int FF = 4096;   // d_ff
static constexpr int BB = 8;      // batch
static constexpr int LL = 1024;   // seq
static constexpr int TT = BB * LL; // 8192 tokens

// ---------- fused phase-1: LN1 + mask-pack + weight cvt + bias concat -------
// Block map: [0,TT) LN rows | [TT,TT+1024) mask-pack | [+6144) weight cvt |
// [+12) bias concat. Pack blocks self-detect mask dtype via 16KB OR-scan.
__global__ __launch_bounds__(256) void prep_ln1_kernel(
    const float* __restrict__ x, const float* __restrict__ sc,
    const float* __restrict__ bi, unsigned short* __restrict__ xnout,
    const void* __restrict__ mask, unsigned* __restrict__ mp,
    const float* __restrict__ Wq, const float* __restrict__ Wk,
    const float* __restrict__ Wv, const float* __restrict__ Wo,
    const float* __restrict__ W1, const float* __restrict__ W2,
    const float* __restrict__ bq, const float* __restrict__ bk,
    const float* __restrict__ bv,
    unsigned short* __restrict__ wqkv, unsigned short* __restrict__ wob,
    unsigned short* __restrict__ w1b, unsigned short* __restrict__ w2b,
    float* __restrict__ bqkv) {
  const int b = blockIdx.x;
  const int t = threadIdx.x;
  if (b < TT) {
    // ---- LayerNorm row ----
    const f32x4* xr = (const f32x4*)(x + (size_t)b * DM);
    f32x4 v = xr[t];
    float s = v[0] + v[1] + v[2] + v[3];
    float q = v[0]*v[0] + v[1]*v[1] + v[2]*v[2] + v[3]*v[3];
    #pragma unroll
    for (int off = 32; off >= 1; off >>= 1) { s += __shfl_xor(s, off); q += __shfl_xor(q, off); }
    __shared__ float red[8];
    int wv = t >> 6;
    if ((t & 63) == 0) { red[wv] = s; red[4 + wv] = q; }
    __syncthreads();
    s = red[0] + red[1] + red[2] + red[3];
    q = red[4] + red[5] + red[6] + red[7];
    float mu = s * (1.0f / DM);
    float var = q * (1.0f / DM) - mu * mu;
    float rs = rsqrtf(var + 1e-5f);
    f32x4 sv = ((const f32x4*)sc)[t], bv_ = ((const f32x4*)bi)[t];
    ushort4v o;
    #pragma unroll
    for (int j = 0; j < 4; ++j) o[j] = f2bf((v[j] - mu) * rs * sv[j] + bv_[j]);
    *(ushort4v*)(xnout + (size_t)b * DM + t * 4) = o;
  } else if (b < TT + 1024) {
    // ---- mask pack with self-detected dtype ----
    unsigned a = 0;
    const unsigned* mi4 = (const unsigned*)mask;
    for (int i = t; i < 4096; i += 256) a |= mi4[i];
    #pragma unroll
    for (int off = 32; off >= 1; off >>= 1) a |= __shfl_xor(a, off);
    __shared__ unsigned sh[4];
    if ((t & 63) == 0) sh[t >> 6] = a;
    __syncthreads();
    unsigned o = sh[0] | sh[1] | sh[2] | sh[3];
    const int cls = (o & 0xFEFEFEFEu) ? 2 : ((o & 0xFFFFFF00u) ? 1 : 0);
    int w = (b - TT) * 256 + t;   // word over B*L*(L/32) = 262144
    unsigned bits = 0u;
    if (cls == 1) {
      const unsigned char* mb = (const unsigned char*)mask + (size_t)w * 32;
      #pragma unroll 8
      for (int i = 0; i < 32; ++i) bits |= (mb[i] ? 1u : 0u) << i;
    } else {
      const unsigned* mi = (const unsigned*)mask + (size_t)w * 32;
      #pragma unroll 8
      for (int i = 0; i < 32; ++i) bits |= (mi[i] ? 1u : 0u) << i;
    }
    mp[w] = bits;
  } else if (b < TT + 1024 + 6144) {
    // ---- weight cvt fp32 -> bf16 ----
    int i = (b - TT - 1024) * 256 + t;
    const float* src; unsigned short* dst; int li;
    if (i < 131072)      { src = Wq; dst = wqkv;             li = i; }
    else if (i < 262144) { src = Wk; dst = wqkv + (1 << 20); li = i - 131072; }
    else if (i < 393216) { src = Wv; dst = wqkv + (2 << 20); li = i - 262144; }
    else if (i < 524288) { src = Wo; dst = wob;              li = i - 393216; }
    else if (i < 1048576){ src = W1; dst = w1b;              li = i - 524288; }
    else                 { src = W2; dst = w2b;              li = i - 1048576; }
    const f32x4* s4 = (const f32x4*)src;
    f32x4 a = s4[li * 2], c = s4[li * 2 + 1];
    short8 o;
    o[0] = (short)f2bf(a[0]); o[1] = (short)f2bf(a[1]);
    o[2] = (short)f2bf(a[2]); o[3] = (short)f2bf(a[3]);
    o[4] = (short)f2bf(c[0]); o[5] = (short)f2bf(c[1]);
    o[6] = (short)f2bf(c[2]); o[7] = (short)f2bf(c[3]);
    *(short8*)(dst + (size_t)li * 8) = o;
  } else {
    // ---- QKV bias concat ----
    int i = (b - TT - 1024 - 6144) * 256 + t;  // 3072
    bqkv[i] = (i < 1024) ? bq[i] : (i < 2048 ? bk[i - 1024] : bv[i - 2048]);
  }
}

// ---------- LayerNorm only (LN2) ----------
__global__ __launch_bounds__(256) void ln_kernel(const float* __restrict__ x,
                                                 const float* __restrict__ sc,
                                                 const float* __restrict__ bi,
                                                 unsigned short* __restrict__ out) {
  int row = blockIdx.x;
  int t = threadIdx.x;
  const f32x4* xr = (const f32x4*)(x + (size_t)row * DM);
  f32x4 v = xr[t];
  float s = v[0] + v[1] + v[2] + v[3];
  float q = v[0]*v[0] + v[1]*v[1] + v[2]*v[2] + v[3]*v[3];
  #pragma unroll
  for (int off = 32; off >= 1; off >>= 1) { s += __shfl_xor(s, off); q += __shfl_xor(q, off); }
  __shared__ float red[8];
  int wv = t >> 6;
  if ((t & 63) == 0) { red[wv] = s; red[4 + wv] = q; }
  __syncthreads();
  s = red[0] + red[1] + red[2] + red[3];
  q = red[4] + red[5] + red[6] + red[7];
  float mu = s * (1.0f / DM);
  float var = q * (1.0f / DM) - mu * mu;
  float rs = rsqrtf(var + 1e-5f);
  f32x4 sv = ((const f32x4*)sc)[t], bv = ((const f32x4*)bi)[t];
  ushort4v o;
  #pragma unroll
  for (int j = 0; j < 4; ++j) o[j] = f2bf((v[j] - mu) * rs * sv[j] + bv[j]);
  *(ushort4v*)(out + (size_t)row * DM + t * 4) = o;
}

// ---------- GEMM v9: 128x128, dbuf pipelined, 2 blocks/CU (round-0 proven) ---
// K=1024 regime verdict (rounds 1-4): the 256^2 8-phase template's verified
// gain at K=1024 is only ~+10% (m248), and both 8-phase ports measured BELOW
// this structure (722 vs 771 TF). Patch swizzle also hurt (FETCH 64.8->82MB).
// This is the round-0 exact structure: linear grid, x-fast (B-panel reuse).
template <int EPI>
__global__ __launch_bounds__(256, 2)
void gemm5(const unsigned short* __restrict__ A, const unsigned short* __restrict__ Bw,
           const float* __restrict__ bias, void* __restrict__ out0,
           void* __restrict__ out1, void* __restrict__ out2,
           const float* __restrict__ res, int N, int K) {
  __shared__ __align__(16) char smem[65536];  // 2 x 32KB
  const int t = threadIdx.x;
  const int w = t >> 6, ln = t & 63;
  const int wm = w >> 1, wn = w & 1;
  const int lg = ln >> 4, lc = ln & 15;
  const int m0 = blockIdx.x * 128, n0 = blockIdx.y * 128;
  const size_t rb = (size_t)K * 2;
  const int nk = K >> 6;

  const char* srcp[8];
  #pragma unroll
  for (int i = 0; i < 8; ++i) {
    int off = i * 4096 + t * 16;
    if (off < 16384) {
      int r = off >> 7, c = (off >> 4) & 7;
      srcp[i] = (const char*)A + (size_t)(m0 + r) * rb + ((c ^ (r & 7)) << 4);
    } else {
      int ob = off - 16384;
      int r = ob >> 7, c = (ob >> 4) & 7;
      srcp[i] = (const char*)Bw + (size_t)(n0 + r) * rb + ((c ^ (r & 7)) << 4);
    }
  }
  auto stage8 = [&](int tile) {
    char* db = smem + ((tile & 1) << 15) + t * 16;
    const size_t ko = (size_t)tile << 7;
    #pragma unroll
    for (int i = 0; i < 8; ++i) gload_lds16(srcp[i] + ko, db + i * 4096);
  };

  int aoff[4][2], boff[4][2];
  #pragma unroll
  for (int x_ = 0; x_ < 4; ++x_)
    #pragma unroll
    for (int kk = 0; kk < 2; ++kk) {
      int ra = wm * 64 + x_ * 16 + lc;
      aoff[x_][kk] = ra * 128 + (((kk * 4 + lg) ^ (ra & 7)) << 4);
      int rn = wn * 64 + x_ * 16 + lc;
      boff[x_][kk] = 16384 + rn * 128 + (((kk * 4 + lg) ^ (rn & 7)) << 4);
    }

  f32x4 acc[4][4] = {};

  stage8(0);
  for (int T = 0; T < nk; ++T) {
    if (T + 1 < nk) stage8(T + 1);
    if (T == nk - 1) { WAITVM(0); } else { WAITVM(8); }  // tile T landed
    BARRIER;
    const char* buf = smem + ((T & 1) << 15);
    short8 afr[4][2], bfr[4][2];
    #pragma unroll
    for (int ni = 0; ni < 4; ++ni) {
      bfr[ni][0] = *(const short8*)(buf + boff[ni][0]);
      bfr[ni][1] = *(const short8*)(buf + boff[ni][1]);
    }
    #pragma unroll
    for (int mi = 0; mi < 4; ++mi) {
      afr[mi][0] = *(const short8*)(buf + aoff[mi][0]);
      afr[mi][1] = *(const short8*)(buf + aoff[mi][1]);
    }
    __builtin_amdgcn_s_setprio(1);
    #pragma unroll
    for (int mi = 0; mi < 4; ++mi)
      #pragma unroll
      for (int ni = 0; ni < 4; ++ni) {
        acc[mi][ni] = MFMA16(afr[mi][0], bfr[ni][0], acc[mi][ni]);
        acc[mi][ni] = MFMA16(afr[mi][1], bfr[ni][1], acc[mi][ni]);
      }
    __builtin_amdgcn_s_setprio(0);
    WAITLGKM0;   // my reads of buf[T&1] retired
    BARRIER;     // ALL waves' reads retired -> stage(T+2) may overwrite it
  }
  __syncthreads();  // epilogue overlay safety

  const int colb = n0 + wn * 64 + lc;
  const int rowb = m0 + wm * 64 + lg * 4;
  if constexpr (EPI >= 2) {
    #pragma unroll
    for (int ni = 0; ni < 4; ++ni) {
      int col = colb + ni * 16;
      float bv = bias[col];
      #pragma unroll
      for (int mi = 0; mi < 4; ++mi)
        #pragma unroll
        for (int rr = 0; rr < 4; ++rr) {
          int row = rowb + mi * 16 + rr;
          float v = acc[mi][ni][rr] + bv;
          if constexpr (EPI == 2)
            ((float*)out0)[(size_t)row * N + col] = res[(size_t)row * N + col] + v;
          else
            ((float*)out0)[(size_t)row * N + col] += v;
        }
    }
  } else {
    short* sl = (short*)(smem + w * 9216);  // 4 x 9216 = 36KB <= 64KB
    const bool isV = (EPI == 0) && (n0 + wn * 64 >= 2048);
    #pragma unroll
    for (int ni = 0; ni < 4; ++ni) {
      float bv = bias[colb + ni * 16];
      #pragma unroll
      for (int mi = 0; mi < 4; ++mi)
        #pragma unroll
        for (int rr = 0; rr < 4; ++rr) {
          int row_l = mi * 16 + lg * 4 + rr;
          int col_l = ni * 16 + lc;
          float v = acc[mi][ni][rr] + bv;
          if constexpr (EPI == 1) {
            float u2 = v * v;
            float mexp = v * (-2.302206744f - 0.102953795f * u2);
            v = v / (1.0f + exp2f(mexp));
          }
          if (isV) sl[col_l * 72 + row_l] = (short)f2bf(v);
          else     sl[row_l * 72 + col_l] = (short)f2bf(v);
        }
    }
    const int s8 = ln >> 3, c8 = ln & 7;
    if constexpr (EPI == 0) {
      const int b_ = m0 >> 10;
      const int l0 = (m0 & 1023) + wm * 64;
      const int h_ = ((n0 + wn * 64) >> 6) & 15;
      const size_t bh = (size_t)(b_ * NH + h_);
      if (n0 + wn * 64 < 2048) {
        char* dst = (char*)((n0 + wn * 64 < 1024) ? out0 : out1) + (((bh << 10) + l0) << 7);
        #pragma unroll
        for (int j = 0; j < 8; ++j) {
          short8 v8 = *(const short8*)(sl + (j * 8 + s8) * 72 + c8 * 8);
          *(short8*)(dst + j * 1024 + ln * 16) = v8;
        }
      } else {
        char* dst = (char*)out2 + bh * 131072 + l0 * 2 + c8 * 16;
        #pragma unroll
        for (int j = 0; j < 8; ++j) {
          short8 v8 = *(const short8*)(sl + (j * 8 + s8) * 72 + c8 * 8);
          *(short8*)(dst + (size_t)(j * 8 + s8) * 2048) = v8;
        }
      }
    } else {
      char* dst = (char*)out0 + (size_t)(m0 + wm * 64) * ((size_t)N * 2) +
                  (size_t)(n0 + wn * 64) * 2 + c8 * 16;
      #pragma unroll
      for (int j = 0; j < 8; ++j) {
        short8 v8 = *(const short8*)(sl + (j * 8 + s8) * 72 + c8 * 8);
        *(short8*)(dst + (size_t)(j * 8 + s8) * ((size_t)N * 2)) = v8;
      }
    }
  }
}

// ---------- flash attention: direct-global V (no V LDS staging) -------------
// Round-5 (kept): counted vmcnt vs per-iter vmcnt(0) drains (-8us).
// Round-6 (kept): setprio(1) around MFMA clusters.
// Round-7 (kept): swapped QK^T -> lane-local softmax row, cvt_pk P-pack.
// Round-8: drop V LDS staging (guide m169: at S=1024, K/V L2-fits and
// V-staging was pure overhead, +26% when dropped). V^T global layout
// [B,H,dk,L] yields the PV B-fragment directly: row=dt*16+lc (stride 2048B),
// 16B chunk at kt*128 + kk*64 + lg*16. XCD swizzle co-locates a head's 8
// blocks on one XCD -> V reads hit that XCD's L2. The 8 V loads issue right
// after QK, hiding L2 latency under softmax. vmcnt stays exact: V loads are
// register-targeted (compiler-tracked, retired by PV uses; in-order
// retirement then implies the older K-stage landed too), so the manual
// counter only tracks the single K gload_lds. LDS drops 51KB -> 34KB.
__global__ __launch_bounds__(512) void attn_kernel(const unsigned short* __restrict__ Q,
                                                   const unsigned short* __restrict__ Kb,
                                                   const unsigned short* __restrict__ Vt,
                                                   const unsigned* __restrict__ mp,
                                                   unsigned short* __restrict__ ctx) {
  __shared__ __align__(16) char kv[2][8192];       // K tile x2 (V is direct-global)
  __shared__ __align__(16) short plds[8][16][72];  // per-wave P tile [q=16][k=64+pad]
  const int t = threadIdx.x, wv = t >> 6, ln = t & 63;
  const int bid = blockIdx.x;
  const int wg = (bid & 7) * 128 + (bid >> 3);     // XCD swizzle (grid 1024)
  const int qt = wg & 7, h_ = (wg >> 3) & 15, b_ = wg >> 7;
  const int bh = b_ * NH + h_;
  const int lg = ln >> 4, lc = ln & 15;
  const int lg4 = lg * 4;
  const int qrow0 = qt * 128 + wv * 16;

  const unsigned short* qbase = Q + ((size_t)bh * LL + qrow0) * DK;
  short8 qf0 = *(const short8*)(qbase + (size_t)lc * DK + lg * 8);
  short8 qf1 = *(const short8*)(qbase + (size_t)lc * DK + 32 + lg * 8);

  short8 onesf;
  #pragma unroll
  for (int j = 0; j < 8; ++j) onesf[j] = (short)0x3F80;  // bf16 1.0

  f32x4 o[4] = {};
  f32x4 o_l = {};  // row sums via ones-column MFMA

  const char* kg = (const char*)(Kb + (size_t)bh * LL * DK);
  const char* vg = (const char*)(Vt + (size_t)bh * DK * LL);
  const int srow = ln >> 3;
  const int gc = (ln & 7) ^ srow;
  const char* ksrc = kg + (size_t)(wv * 8 + srow) * 128 + gc * 16;
  // loop-invariant V row pointers: row d = dt*16+lc, per-lane k-chunk lg*16
  const char* vrow[4];
  #pragma unroll
  for (int dt = 0; dt < 4; ++dt)
    vrow[dt] = vg + (size_t)(dt * 16 + lc) * 2048 + lg * 16;

  // per-lane mask row: this lane's q-row = qrow0 + lc (32 words per row)
  const unsigned* mrow = mp + ((size_t)b_ * LL + qrow0 + lc) * 32;

  gload_lds16(ksrc, kv[0] + wv * 1024);
  __syncthreads();   // prologue: K tile 0 landed (drains vmcnt)

  int cur = 0;
  for (int kt = 0; kt < 16; ++kt) {
    if (kt < 15) {
      gload_lds16(ksrc + (size_t)(kt + 1) * 8192, kv[cur ^ 1] + wv * 1024);
      WAITVM(1);   // K(kt) landed (V loads already retired by prev PV uses)
    } else {
      WAITVM(0);
    }
    BARRIER;       // all waves' K stages landed -> kv[cur] complete
    const char* kb_ = kv[cur];
    const unsigned w0 = mrow[kt * 2], w1 = mrow[kt * 2 + 1];
    f32x4 s[4] = {};
    __builtin_amdgcn_s_setprio(1);
    #pragma unroll
    for (int c = 0; c < 4; ++c) {
      int row = c * 16 + lc;
      short8 k0 = *(const short8*)(kb_ + row * 128 + ((lg) ^ (row & 7)) * 16);
      short8 k1 = *(const short8*)(kb_ + row * 128 + ((4 + lg) ^ (row & 7)) * 16);
      s[c] = MFMA16(k0, qf0, s[c]);   // SWAPPED: S^T[k=c*16+lg4+r][q=lc]
      s[c] = MFMA16(k1, qf1, s[c]);
    }
    __builtin_amdgcn_s_setprio(0);
    // issue V fragment loads now -- L2 latency hides under softmax + P-pack
    short8 vf[2][4];
    #pragma unroll
    for (int kk = 0; kk < 2; ++kk)
      #pragma unroll
      for (int dt = 0; dt < 4; ++dt)
        vf[kk][dt] = *(const short8*)(vrow[dt] + kt * 128 + kk * 64);
    #pragma unroll
    for (int c = 0; c < 4; ++c) {
      const unsigned wsel = (c >= 2) ? w1 : w0;
      float p[4];
      #pragma unroll
      for (int r = 0; r < 4; ++r) {
        bool mk = (wsel >> ((c & 1) * 16 + lg4 + r)) & 1;
        p[r] = mk ? 0.0f : exp2f(fmaf(s[c][r], 0.18033688011112f, -16.0f));
      }
      unsigned plo, phi;
      asm("v_cvt_pk_bf16_f32 %0, %1, %2" : "=v"(plo) : "v"(p[0]), "v"(p[1]));
      asm("v_cvt_pk_bf16_f32 %0, %1, %2" : "=v"(phi) : "v"(p[2]), "v"(p[3]));
      uint2v pk; pk[0] = plo; pk[1] = phi;
      *(uint2v*)&plds[wv][lc][c * 16 + lg4] = pk;   // 4 consecutive k, b64
    }
    __builtin_amdgcn_s_setprio(1);
    #pragma unroll
    for (int kk = 0; kk < 2; ++kk) {
      short8 pf = *(const short8*)&plds[wv][lc][kk * 32 + lg * 8];
      o_l = MFMA16(pf, onesf, o_l);
      #pragma unroll
      for (int dt = 0; dt < 4; ++dt)
        o[dt] = MFMA16(pf, vf[kk][dt], o[dt]);
    }
    __builtin_amdgcn_s_setprio(0);
    WAITLGKM0;     // my LDS reads of kv[cur] retired
    BARRIER;       // all waves done with kv[cur] -> next K stage may overwrite
    cur ^= 1;
  }
  #pragma unroll
  for (int r = 0; r < 4; ++r) {
    float l = o_l[r];
    float inv = (l > 0.0f) ? 1.0f / l : 0.0f;
    size_t trow = (size_t)b_ * LL + qt * 128 + wv * 16 + lg * 4 + r;
    #pragma unroll
    for (int dt = 0; dt < 4; ++dt)
      ctx[trow * DM + h_ * 64 + dt * 16 + lc] = f2bf(o[dt][r] * inv);
  }
}

// ---------- launch ----------
extern "C" void kernel_launch(void* const* d_in, const int* in_sizes, int n_in,
                              void* d_out, int out_size, void* d_ws, size_t ws_size,
                              hipStream_t stream) {
  const float* x   = (const float*)d_in[0];
  const void*  msk = d_in[1];
  const float* Wq = (const float*)d_in[2],  *bq = (const float*)d_in[3];
  const float* Wk = (const float*)d_in[4],  *bk = (const float*)d_in[5];
  const float* Wv = (const float*)d_in[6],  *bv = (const float*)d_in[7];
  const float* Wo = (const float*)d_in[8],  *bo = (const float*)d_in[9];
  const float* l1s = (const float*)d_in[10], *l1b = (const float*)d_in[11];
  const float* l2s = (const float*)d_in[12], *l2b = (const float*)d_in[13];
  const float* W1 = (const float*)d_in[14], *b1 = (const float*)d_in[15];
  const float* W2 = (const float*)d_in[16], *b2 = (const float*)d_in[17];
  float* out = (float*)d_out;
  char* ws = (char*)d_ws;
  const size_t MB = 1u << 20;

  unsigned short* wqkv = (unsigned short*)(ws + 0 * MB);  // 6MB (Wq|Wk|Wv rows)
  unsigned short* wob = (unsigned short*)(ws + 6 * MB);   // 2MB
  unsigned short* w1b = (unsigned short*)(ws + 8 * MB);   // 8MB
  unsigned short* w2b = (unsigned short*)(ws + 16 * MB);  // 8MB
  unsigned short* xn  = (unsigned short*)(ws + 24 * MB);  // 16MB (reused as ctx)
  unsigned short* qb  = (unsigned short*)(ws + 40 * MB);  // 16MB (reused as xn2)
  unsigned short* kb  = (unsigned short*)(ws + 56 * MB);  // 16MB
  unsigned short* vtb = (unsigned short*)(ws + 72 * MB);  // 16MB
  unsigned*       mpk = (unsigned*)(ws + 88 * MB);        // 1MB
  float*          bqkv = (float*)(ws + 89 * MB);          // 12KB
  unsigned short* ctx = xn;
  unsigned short* xn2 = qb;
  unsigned short* hb  = (unsigned short*)(ws + 90 * MB);  // mchunk*4096*2

  int mchunk;
  size_t avail = (ws_size > 90 * MB) ? ws_size - 90 * MB : 0;
  if      (avail >= 64 * MB) mchunk = 8192;
  else if (avail >= 16 * MB) mchunk = 2048;
  else if (avail >= 4 * MB)  mchunk = 512;
  else                       mchunk = 256;

  // fused phase-1: LN1 + mask pack + weight cvt + bias concat (one launch)
  prep_ln1_kernel<<<TT + 1024 + 6144 + 12, 256, 0, stream>>>(
      x, l1s, l1b, xn, msk, mpk,
      Wq, Wk, Wv, Wo, W1, W2, bq, bk, bv,
      wqkv, wob, w1b, w2b, bqkv);

  // fused QKV projection (M=8192, N=3072, K=1024)
  gemm5<0><<<dim3(64, 24), 256, 0, stream>>>(xn, wqkv, bqkv, qb, kb, vtb,
                                             nullptr, 3072, DM);

  // attention (1024 blocks: 8 b * 16 h * 8 q-tiles of 128 rows)
  attn_kernel<<<1024, 512, 0, stream>>>(qb, kb, vtb, mpk, ctx);

  // Wo + residual -> d_out (fp32)
  gemm5<2><<<dim3(64, 8), 256, 0, stream>>>(ctx, wob, bo, out, nullptr, nullptr,
                                            x, DM, DM);

  // LN2
  ln_kernel<<<TT, 256, 0, stream>>>(out, l2s, l2b, xn2);

  // FFN, chunked over M to bound scratch
  for (int off = 0; off < TT; off += mchunk) {
    gemm5<1><<<dim3(mchunk / 128, 32), 256, 0, stream>>>(
        xn2 + (size_t)off * DM, w1b, b1, hb, nullptr, nullptr, nullptr, FF, DM);
    gemm5<3><<<dim3(mchunk / 128, 8), 256, 0, stream>>>(
        hb, w2b, b2, out + (size_t)off * DM, nullptr, nullptr, nullptr, DM, FF);
  }
}

// Round 9
// 376.054 us; speedup vs baseline: 1.1731x; 1.1731x over previous
//
#include <hip/hip_runtime.h>
#include <cstdint>
#include <cstddef>

// ---------- types ----------
typedef __attribute__((ext_vector_type(8))) short short8;     // 8 x bf16
typedef __attribute__((ext_vector_type(4))) float f32x4;
typedef __attribute__((ext_vector_type(4))) unsigned short ushort4v;
typedef __attribute__((ext_vector_type(2))) unsigned uint2v;

#define DEVI __device__ __forceinline__

DEVI unsigned short f2bf(float f) {  // RNE f32 -> bf16 bits
  union { float f; unsigned u; } x; x.f = f;
  unsigned r = x.u + 0x7fffu + ((x.u >> 16) & 1u);
  return (unsigned short)(r >> 16);
}

#define MFMA16(a, b, c) __builtin_amdgcn_mfma_f32_16x16x32_bf16(a, b, c, 0, 0, 0)
#define FENCE asm volatile("" ::: "memory")
#define WAITVM(n) asm volatile("s_waitcnt vmcnt(" #n ")" ::: "memory")
#define WAITLGKM0 asm volatile("s_waitcnt lgkmcnt(0)" ::: "memory")
#define BARRIER do { FENCE; __builtin_amdgcn_s_barrier(); FENCE; } while (0)

typedef __attribute__((address_space(1))) const void g_void;
typedef __attribute__((address_space(3))) void lds_void;
DEVI void gload_lds16(const void* g, void* l) {
  __builtin_amdgcn_global_load_lds((g_void*)g, (lds_void*)l, 16, 0, 0);
}

// ---------- constants ----------
static constexpr int DM = 1024;   // d_model
static constexpr int NH = 16;     // heads
static constexpr int DK = 64;     // head dim
static constexpr int FF = 4096;   // d_ff
static constexpr int BB = 8;      // batch
static constexpr int LL = 1024;   // seq
static constexpr int TT = BB * LL; // 8192 tokens

// ---------- fused phase-1: LN1 + mask-pack + weight cvt + bias concat -------
// Block map: [0,TT) LN rows | [TT,TT+1024) mask-pack | [+6144) weight cvt |
// [+12) bias concat. Pack blocks self-detect mask dtype via 16KB OR-scan.
__global__ __launch_bounds__(256) void prep_ln1_kernel(
    const float* __restrict__ x, const float* __restrict__ sc,
    const float* __restrict__ bi, unsigned short* __restrict__ xnout,
    const void* __restrict__ mask, unsigned* __restrict__ mp,
    const float* __restrict__ Wq, const float* __restrict__ Wk,
    const float* __restrict__ Wv, const float* __restrict__ Wo,
    const float* __restrict__ W1, const float* __restrict__ W2,
    const float* __restrict__ bq, const float* __restrict__ bk,
    const float* __restrict__ bv,
    unsigned short* __restrict__ wqkv, unsigned short* __restrict__ wob,
    unsigned short* __restrict__ w1b, unsigned short* __restrict__ w2b,
    float* __restrict__ bqkv) {
  const int b = blockIdx.x;
  const int t = threadIdx.x;
  if (b < TT) {
    // ---- LayerNorm row ----
    const f32x4* xr = (const f32x4*)(x + (size_t)b * DM);
    f32x4 v = xr[t];
    float s = v[0] + v[1] + v[2] + v[3];
    float q = v[0]*v[0] + v[1]*v[1] + v[2]*v[2] + v[3]*v[3];
    #pragma unroll
    for (int off = 32; off >= 1; off >>= 1) { s += __shfl_xor(s, off); q += __shfl_xor(q, off); }
    __shared__ float red[8];
    int wv = t >> 6;
    if ((t & 63) == 0) { red[wv] = s; red[4 + wv] = q; }
    __syncthreads();
    s = red[0] + red[1] + red[2] + red[3];
    q = red[4] + red[5] + red[6] + red[7];
    float mu = s * (1.0f / DM);
    float var = q * (1.0f / DM) - mu * mu;
    float rs = rsqrtf(var + 1e-5f);
    f32x4 sv = ((const f32x4*)sc)[t], bv_ = ((const f32x4*)bi)[t];
    ushort4v o;
    #pragma unroll
    for (int j = 0; j < 4; ++j) o[j] = f2bf((v[j] - mu) * rs * sv[j] + bv_[j]);
    *(ushort4v*)(xnout + (size_t)b * DM + t * 4) = o;
  } else if (b < TT + 1024) {
    // ---- mask pack with self-detected dtype ----
    unsigned a = 0;
    const unsigned* mi4 = (const unsigned*)mask;
    for (int i = t; i < 4096; i += 256) a |= mi4[i];
    #pragma unroll
    for (int off = 32; off >= 1; off >>= 1) a |= __shfl_xor(a, off);
    __shared__ unsigned sh[4];
    if ((t & 63) == 0) sh[t >> 6] = a;
    __syncthreads();
    unsigned o = sh[0] | sh[1] | sh[2] | sh[3];
    const int cls = (o & 0xFEFEFEFEu) ? 2 : ((o & 0xFFFFFF00u) ? 1 : 0);
    int w = (b - TT) * 256 + t;   // word over B*L*(L/32) = 262144
    unsigned bits = 0u;
    if (cls == 1) {
      const unsigned char* mb = (const unsigned char*)mask + (size_t)w * 32;
      #pragma unroll 8
      for (int i = 0; i < 32; ++i) bits |= (mb[i] ? 1u : 0u) << i;
    } else {
      const unsigned* mi = (const unsigned*)mask + (size_t)w * 32;
      #pragma unroll 8
      for (int i = 0; i < 32; ++i) bits |= (mi[i] ? 1u : 0u) << i;
    }
    mp[w] = bits;
  } else if (b < TT + 1024 + 6144) {
    // ---- weight cvt fp32 -> bf16 ----
    int i = (b - TT - 1024) * 256 + t;
    const float* src; unsigned short* dst; int li;
    if (i < 131072)      { src = Wq; dst = wqkv;             li = i; }
    else if (i < 262144) { src = Wk; dst = wqkv + (1 << 20); li = i - 131072; }
    else if (i < 393216) { src = Wv; dst = wqkv + (2 << 20); li = i - 262144; }
    else if (i < 524288) { src = Wo; dst = wob;              li = i - 393216; }
    else if (i < 1048576){ src = W1; dst = w1b;              li = i - 524288; }
    else                 { src = W2; dst = w2b;              li = i - 1048576; }
    const f32x4* s4 = (const f32x4*)src;
    f32x4 a = s4[li * 2], c = s4[li * 2 + 1];
    short8 o;
    o[0] = (short)f2bf(a[0]); o[1] = (short)f2bf(a[1]);
    o[2] = (short)f2bf(a[2]); o[3] = (short)f2bf(a[3]);
    o[4] = (short)f2bf(c[0]); o[5] = (short)f2bf(c[1]);
    o[6] = (short)f2bf(c[2]); o[7] = (short)f2bf(c[3]);
    *(short8*)(dst + (size_t)li * 8) = o;
  } else {
    // ---- QKV bias concat ----
    int i = (b - TT - 1024 - 6144) * 256 + t;  // 3072
    bqkv[i] = (i < 1024) ? bq[i] : (i < 2048 ? bk[i - 1024] : bv[i - 2048]);
  }
}

// ---------- LayerNorm only (LN2) ----------
__global__ __launch_bounds__(256) void ln_kernel(const float* __restrict__ x,
                                                 const float* __restrict__ sc,
                                                 const float* __restrict__ bi,
                                                 unsigned short* __restrict__ out) {
  int row = blockIdx.x;
  int t = threadIdx.x;
  const f32x4* xr = (const f32x4*)(x + (size_t)row * DM);
  f32x4 v = xr[t];
  float s = v[0] + v[1] + v[2] + v[3];
  float q = v[0]*v[0] + v[1]*v[1] + v[2]*v[2] + v[3]*v[3];
  #pragma unroll
  for (int off = 32; off >= 1; off >>= 1) { s += __shfl_xor(s, off); q += __shfl_xor(q, off); }
  __shared__ float red[8];
  int wv = t >> 6;
  if ((t & 63) == 0) { red[wv] = s; red[4 + wv] = q; }
  __syncthreads();
  s = red[0] + red[1] + red[2] + red[3];
  q = red[4] + red[5] + red[6] + red[7];
  float mu = s * (1.0f / DM);
  float var = q * (1.0f / DM) - mu * mu;
  float rs = rsqrtf(var + 1e-5f);
  f32x4 sv = ((const f32x4*)sc)[t], bv = ((const f32x4*)bi)[t];
  ushort4v o;
  #pragma unroll
  for (int j = 0; j < 4; ++j) o[j] = f2bf((v[j] - mu) * rs * sv[j] + bv[j]);
  *(ushort4v*)(out + (size_t)row * DM + t * 4) = o;
}

// ---------- GEMM v9: 128x128, dbuf pipelined, 2 blocks/CU (round-0 proven) ---
// K=1024 regime verdict (rounds 1-4): the 256^2 8-phase template's verified
// gain at K=1024 is only ~+10% (m248), and both 8-phase ports measured BELOW
// this structure (722 vs 771 TF). Patch swizzle also hurt (FETCH 64.8->82MB).
// This is the round-0 exact structure: linear grid, x-fast (B-panel reuse).
template <int EPI>
__global__ __launch_bounds__(256, 2)
void gemm5(const unsigned short* __restrict__ A, const unsigned short* __restrict__ Bw,
           const float* __restrict__ bias, void* __restrict__ out0,
           void* __restrict__ out1, void* __restrict__ out2,
           const float* __restrict__ res, int N, int K) {
  __shared__ __align__(16) char smem[65536];  // 2 x 32KB
  const int t = threadIdx.x;
  const int w = t >> 6, ln = t & 63;
  const int wm = w >> 1, wn = w & 1;
  const int lg = ln >> 4, lc = ln & 15;
  const int m0 = blockIdx.x * 128, n0 = blockIdx.y * 128;
  const size_t rb = (size_t)K * 2;
  const int nk = K >> 6;

  const char* srcp[8];
  #pragma unroll
  for (int i = 0; i < 8; ++i) {
    int off = i * 4096 + t * 16;
    if (off < 16384) {
      int r = off >> 7, c = (off >> 4) & 7;
      srcp[i] = (const char*)A + (size_t)(m0 + r) * rb + ((c ^ (r & 7)) << 4);
    } else {
      int ob = off - 16384;
      int r = ob >> 7, c = (ob >> 4) & 7;
      srcp[i] = (const char*)Bw + (size_t)(n0 + r) * rb + ((c ^ (r & 7)) << 4);
    }
  }
  auto stage8 = [&](int tile) {
    char* db = smem + ((tile & 1) << 15) + t * 16;
    const size_t ko = (size_t)tile << 7;
    #pragma unroll
    for (int i = 0; i < 8; ++i) gload_lds16(srcp[i] + ko, db + i * 4096);
  };

  int aoff[4][2], boff[4][2];
  #pragma unroll
  for (int x_ = 0; x_ < 4; ++x_)
    #pragma unroll
    for (int kk = 0; kk < 2; ++kk) {
      int ra = wm * 64 + x_ * 16 + lc;
      aoff[x_][kk] = ra * 128 + (((kk * 4 + lg) ^ (ra & 7)) << 4);
      int rn = wn * 64 + x_ * 16 + lc;
      boff[x_][kk] = 16384 + rn * 128 + (((kk * 4 + lg) ^ (rn & 7)) << 4);
    }

  f32x4 acc[4][4] = {};

  stage8(0);
  for (int T = 0; T < nk; ++T) {
    if (T + 1 < nk) stage8(T + 1);
    if (T == nk - 1) { WAITVM(0); } else { WAITVM(8); }  // tile T landed
    BARRIER;
    const char* buf = smem + ((T & 1) << 15);
    short8 afr[4][2], bfr[4][2];
    #pragma unroll
    for (int ni = 0; ni < 4; ++ni) {
      bfr[ni][0] = *(const short8*)(buf + boff[ni][0]);
      bfr[ni][1] = *(const short8*)(buf + boff[ni][1]);
    }
    #pragma unroll
    for (int mi = 0; mi < 4; ++mi) {
      afr[mi][0] = *(const short8*)(buf + aoff[mi][0]);
      afr[mi][1] = *(const short8*)(buf + aoff[mi][1]);
    }
    __builtin_amdgcn_s_setprio(1);
    #pragma unroll
    for (int mi = 0; mi < 4; ++mi)
      #pragma unroll
      for (int ni = 0; ni < 4; ++ni) {
        acc[mi][ni] = MFMA16(afr[mi][0], bfr[ni][0], acc[mi][ni]);
        acc[mi][ni] = MFMA16(afr[mi][1], bfr[ni][1], acc[mi][ni]);
      }
    __builtin_amdgcn_s_setprio(0);
    WAITLGKM0;   // my reads of buf[T&1] retired
    BARRIER;     // ALL waves' reads retired -> stage(T+2) may overwrite it
  }
  __syncthreads();  // epilogue overlay safety

  const int colb = n0 + wn * 64 + lc;
  const int rowb = m0 + wm * 64 + lg * 4;
  if constexpr (EPI >= 2) {
    #pragma unroll
    for (int ni = 0; ni < 4; ++ni) {
      int col = colb + ni * 16;
      float bv = bias[col];
      #pragma unroll
      for (int mi = 0; mi < 4; ++mi)
        #pragma unroll
        for (int rr = 0; rr < 4; ++rr) {
          int row = rowb + mi * 16 + rr;
          float v = acc[mi][ni][rr] + bv;
          if constexpr (EPI == 2)
            ((float*)out0)[(size_t)row * N + col] = res[(size_t)row * N + col] + v;
          else
            ((float*)out0)[(size_t)row * N + col] += v;
        }
    }
  } else {
    short* sl = (short*)(smem + w * 9216);  // 4 x 9216 = 36KB <= 64KB
    const bool isV = (EPI == 0) && (n0 + wn * 64 >= 2048);
    #pragma unroll
    for (int ni = 0; ni < 4; ++ni) {
      float bv = bias[colb + ni * 16];
      #pragma unroll
      for (int mi = 0; mi < 4; ++mi)
        #pragma unroll
        for (int rr = 0; rr < 4; ++rr) {
          int row_l = mi * 16 + lg * 4 + rr;
          int col_l = ni * 16 + lc;
          float v = acc[mi][ni][rr] + bv;
          if constexpr (EPI == 1) {
            float u2 = v * v;
            float mexp = v * (-2.302206744f - 0.102953795f * u2);
            v = v / (1.0f + exp2f(mexp));
          }
          if (isV) sl[col_l * 72 + row_l] = (short)f2bf(v);
          else     sl[row_l * 72 + col_l] = (short)f2bf(v);
        }
    }
    const int s8 = ln >> 3, c8 = ln & 7;
    if constexpr (EPI == 0) {
      const int b_ = m0 >> 10;
      const int l0 = (m0 & 1023) + wm * 64;
      const int h_ = ((n0 + wn * 64) >> 6) & 15;
      const size_t bh = (size_t)(b_ * NH + h_);
      if (n0 + wn * 64 < 2048) {
        char* dst = (char*)((n0 + wn * 64 < 1024) ? out0 : out1) + (((bh << 10) + l0) << 7);
        #pragma unroll
        for (int j = 0; j < 8; ++j) {
          short8 v8 = *(const short8*)(sl + (j * 8 + s8) * 72 + c8 * 8);
          *(short8*)(dst + j * 1024 + ln * 16) = v8;
        }
      } else {
        char* dst = (char*)out2 + bh * 131072 + l0 * 2 + c8 * 16;
        #pragma unroll
        for (int j = 0; j < 8; ++j) {
          short8 v8 = *(const short8*)(sl + (j * 8 + s8) * 72 + c8 * 8);
          *(short8*)(dst + (size_t)(j * 8 + s8) * 2048) = v8;
        }
      }
    } else {
      char* dst = (char*)out0 + (size_t)(m0 + wm * 64) * ((size_t)N * 2) +
                  (size_t)(n0 + wn * 64) * 2 + c8 * 16;
      #pragma unroll
      for (int j = 0; j < 8; ++j) {
        short8 v8 = *(const short8*)(sl + (j * 8 + s8) * 72 + c8 * 8);
        *(short8*)(dst + (size_t)(j * 8 + s8) * ((size_t)N * 2)) = v8;
      }
    }
  }
}

// ---------- flash attention: swapped-QK^T softmax (round-7 state, reverted) -
// Round-5 (kept): counted WAITVM(2) vs per-iter vmcnt(0) drains (-8us).
// Round-6 (kept): setprio(1) around MFMA clusters.
// Round-7 (kept): swapped QK^T -> lane-local softmax row, cvt_pk P-pack.
// Round-8 REVERTED: direct-global V (no LDS) cost 2x (70->148us): V LDS
// staging is a 1-load-8-consumer broadcast across the block's waves;
// dropping it created 8x intra-block request amplification + per-iteration
// L2 latency exposure (MfmaUtil 10.5%, FETCH only 25MB -> latency-bound,
// not BW-bound). m169's "drop V-staging" datapoint was a 1-wave-per-block
// kernel where staging had no sharing value -- regime mismatch.
__global__ __launch_bounds__(512) void attn_kernel(const unsigned short* __restrict__ Q,
                                                   const unsigned short* __restrict__ Kb,
                                                   const unsigned short* __restrict__ Vt,
                                                   const unsigned* __restrict__ mp,
                                                   unsigned short* __restrict__ ctx) {
  __shared__ __align__(16) char kv[2][16384];      // [K tile 8KB | V tile 8KB] x2
  __shared__ __align__(16) short plds[8][16][72];  // per-wave P tile [q=16][k=64+pad]
  const int t = threadIdx.x, wv = t >> 6, ln = t & 63;
  const int bid = blockIdx.x;
  const int wg = (bid & 7) * 128 + (bid >> 3);     // XCD swizzle (grid 1024)
  const int qt = wg & 7, h_ = (wg >> 3) & 15, b_ = wg >> 7;
  const int bh = b_ * NH + h_;
  const int lg = ln >> 4, lc = ln & 15;
  const int lg4 = lg * 4;
  const int qrow0 = qt * 128 + wv * 16;

  const unsigned short* qbase = Q + ((size_t)bh * LL + qrow0) * DK;
  short8 qf0 = *(const short8*)(qbase + (size_t)lc * DK + lg * 8);
  short8 qf1 = *(const short8*)(qbase + (size_t)lc * DK + 32 + lg * 8);

  short8 onesf;
  #pragma unroll
  for (int j = 0; j < 8; ++j) onesf[j] = (short)0x3F80;  // bf16 1.0

  f32x4 o[4] = {};
  f32x4 o_l = {};  // row sums via ones-column MFMA

  const char* kg = (const char*)(Kb + (size_t)bh * LL * DK);
  const char* vg = (const char*)(Vt + (size_t)bh * DK * LL);
  const int srow = ln >> 3;
  const int gc = (ln & 7) ^ srow;
  const char* ksrc = kg + (size_t)(wv * 8 + srow) * 128 + gc * 16;
  const char* vsrc = vg + (size_t)(wv * 8 + srow) * 2048 + gc * 16;

  // per-lane mask row: this lane's q-row = qrow0 + lc (32 words per row)
  const unsigned* mrow = mp + ((size_t)b_ * LL + qrow0 + lc) * 32;

  gload_lds16(ksrc, kv[0] + wv * 1024);
  gload_lds16(vsrc, kv[0] + 8192 + wv * 1024);
  __syncthreads();   // prologue: tile 0 landed (drains vmcnt)

  int cur = 0;
  for (int kt = 0; kt < 16; ++kt) {
    if (kt < 15) {
      gload_lds16(ksrc + (size_t)(kt + 1) * 8192, kv[cur ^ 1] + wv * 1024);
      gload_lds16(vsrc + (size_t)(kt + 1) * 128, kv[cur ^ 1] + 8192 + wv * 1024);
      WAITVM(2);   // previous tile's 2 loads landed; new 2 stay in flight
    } else {
      WAITVM(0);   // last tile: drain the final prefetch
    }
    BARRIER;       // all waves' stages landed -> kv[cur] complete
    const char* kb_ = kv[cur];
    const char* vb_ = kv[cur] + 8192;
    const unsigned w0 = mrow[kt * 2], w1 = mrow[kt * 2 + 1];
    f32x4 s[4] = {};
    __builtin_amdgcn_s_setprio(1);
    #pragma unroll
    for (int c = 0; c < 4; ++c) {
      int row = c * 16 + lc;
      short8 k0 = *(const short8*)(kb_ + row * 128 + ((lg) ^ (row & 7)) * 16);
      short8 k1 = *(const short8*)(kb_ + row * 128 + ((4 + lg) ^ (row & 7)) * 16);
      s[c] = MFMA16(k0, qf0, s[c]);   // SWAPPED: S^T[k=c*16+lg4+r][q=lc]
      s[c] = MFMA16(k1, qf1, s[c]);
    }
    __builtin_amdgcn_s_setprio(0);
    #pragma unroll
    for (int c = 0; c < 4; ++c) {
      const unsigned wsel = (c >= 2) ? w1 : w0;
      float p[4];
      #pragma unroll
      for (int r = 0; r < 4; ++r) {
        bool mk = (wsel >> ((c & 1) * 16 + lg4 + r)) & 1;
        p[r] = mk ? 0.0f : exp2f(fmaf(s[c][r], 0.18033688011112f, -16.0f));
      }
      unsigned plo, phi;
      asm("v_cvt_pk_bf16_f32 %0, %1, %2" : "=v"(plo) : "v"(p[0]), "v"(p[1]));
      asm("v_cvt_pk_bf16_f32 %0, %1, %2" : "=v"(phi) : "v"(p[2]), "v"(p[3]));
      uint2v pk; pk[0] = plo; pk[1] = phi;
      *(uint2v*)&plds[wv][lc][c * 16 + lg4] = pk;   // 4 consecutive k, b64
    }
    __builtin_amdgcn_s_setprio(1);
    #pragma unroll
    for (int kk = 0; kk < 2; ++kk) {
      short8 pf = *(const short8*)&plds[wv][lc][kk * 32 + lg * 8];
      o_l = MFMA16(pf, onesf, o_l);
      #pragma unroll
      for (int dt = 0; dt < 4; ++dt) {
        int row = dt * 16 + lc;
        short8 vf = *(const short8*)(vb_ + row * 128 + ((kk * 4 + lg) ^ (row & 7)) * 16);
        o[dt] = MFMA16(pf, vf, o[dt]);
      }
    }
    __builtin_amdgcn_s_setprio(0);
    WAITLGKM0;     // my LDS reads of kv[cur] retired
    BARRIER;       // all waves done with kv[cur] -> next stage may overwrite
    cur ^= 1;
  }
  #pragma unroll
  for (int r = 0; r < 4; ++r) {
    float l = o_l[r];
    float inv = (l > 0.0f) ? 1.0f / l : 0.0f;
    size_t trow = (size_t)b_ * LL + qt * 128 + wv * 16 + lg * 4 + r;
    #pragma unroll
    for (int dt = 0; dt < 4; ++dt)
      ctx[trow * DM + h_ * 64 + dt * 16 + lc] = f2bf(o[dt][r] * inv);
  }
}

// ---------- launch ----------
extern "C" void kernel_launch(void* const* d_in, const int* in_sizes, int n_in,
                              void* d_out, int out_size, void* d_ws, size_t ws_size,
                              hipStream_t stream) {
  const float* x   = (const float*)d_in[0];
  const void*  msk = d_in[1];
  const float* Wq = (const float*)d_in[2],  *bq = (const float*)d_in[3];
  const float* Wk = (const float*)d_in[4],  *bk = (const float*)d_in[5];
  const float* Wv = (const float*)d_in[6],  *bv = (const float*)d_in[7];
  const float* Wo = (const float*)d_in[8],  *bo = (const float*)d_in[9];
  const float* l1s = (const float*)d_in[10], *l1b = (const float*)d_in[11];
  const float* l2s = (const float*)d_in[12], *l2b = (const float*)d_in[13];
  const float* W1 = (const float*)d_in[14], *b1 = (const float*)d_in[15];
  const float* W2 = (const float*)d_in[16], *b2 = (const float*)d_in[17];
  float* out = (float*)d_out;
  char* ws = (char*)d_ws;
  const size_t MB = 1u << 20;

  unsigned short* wqkv = (unsigned short*)(ws + 0 * MB);  // 6MB (Wq|Wk|Wv rows)
  unsigned short* wob = (unsigned short*)(ws + 6 * MB);   // 2MB
  unsigned short* w1b = (unsigned short*)(ws + 8 * MB);   // 8MB
  unsigned short* w2b = (unsigned short*)(ws + 16 * MB);  // 8MB
  unsigned short* xn  = (unsigned short*)(ws + 24 * MB);  // 16MB (reused as ctx)
  unsigned short* qb  = (unsigned short*)(ws + 40 * MB);  // 16MB (reused as xn2)
  unsigned short* kb  = (unsigned short*)(ws + 56 * MB);  // 16MB
  unsigned short* vtb = (unsigned short*)(ws + 72 * MB);  // 16MB
  unsigned*       mpk = (unsigned*)(ws + 88 * MB);        // 1MB
  float*          bqkv = (float*)(ws + 89 * MB);          // 12KB
  unsigned short* ctx = xn;
  unsigned short* xn2 = qb;
  unsigned short* hb  = (unsigned short*)(ws + 90 * MB);  // mchunk*4096*2

  int mchunk;
  size_t avail = (ws_size > 90 * MB) ? ws_size - 90 * MB : 0;
  if      (avail >= 64 * MB) mchunk = 8192;
  else if (avail >= 16 * MB) mchunk = 2048;
  else if (avail >= 4 * MB)  mchunk = 512;
  else                       mchunk = 256;

  // fused phase-1: LN1 + mask pack + weight cvt + bias concat (one launch)
  prep_ln1_kernel<<<TT + 1024 + 6144 + 12, 256, 0, stream>>>(
      x, l1s, l1b, xn, msk, mpk,
      Wq, Wk, Wv, Wo, W1, W2, bq, bk, bv,
      wqkv, wob, w1b, w2b, bqkv);

  // fused QKV projection (M=8192, N=3072, K=1024)
  gemm5<0><<<dim3(64, 24), 256, 0, stream>>>(xn, wqkv, bqkv, qb, kb, vtb,
                                             nullptr, 3072, DM);

  // attention (1024 blocks: 8 b * 16 h * 8 q-tiles of 128 rows)
  attn_kernel<<<1024, 512, 0, stream>>>(qb, kb, vtb, mpk, ctx);

  // Wo + residual -> d_out (fp32)
  gemm5<2><<<dim3(64, 8), 256, 0, stream>>>(ctx, wob, bo, out, nullptr, nullptr,
                                            x, DM, DM);

  // LN2
  ln_kernel<<<TT, 256, 0, stream>>>(out, l2s, l2b, xn2);

  // FFN, chunked over M to bound scratch
  for (int off = 0; off < TT; off += mchunk) {
    gemm5<1><<<dim3(mchunk / 128, 32), 256, 0, stream>>>(
        xn2 + (size_t)off * DM, w1b, b1, hb, nullptr, nullptr, nullptr, FF, DM);
    gemm5<3><<<dim3(mchunk / 128, 8), 256, 0, stream>>>(
        hb, w2b, b2, out + (size_t)off * DM, nullptr, nullptr, nullptr, DM, FF);
  }
}